// Round 3
// baseline (960.059 us; speedup 1.0000x reference)
//
#include <hip/hip_runtime.h>

// forward_warp bilinear scatter-add, LDS-privatized by destination tile.
// im0: [B,C,H,W] fp32, flow: [B,H,W,2] fp32 (dx,dy), out: [B,C,H,W] fp32
// B=8, C=16, H=512, W=512
//
// R3: record-outer / channel-inner. Each block owns a 32x32 dest tile and a
// 64 KB LDS accumulator covering ALL 16 channels. Each thread processes a
// source record fully in registers (no LDS record staging): 16 independent
// plane-strided loads of v[c] (one latency window), then 64 branchless
// ds_add_f32 with per-corner clamped addresses (out-of-tile corners have
// weight 0.0 -> numeric no-op at a safe address). 2 barriers per block.
// Long-range sources (|flow| >= RAD) handled by global-atomic fallback.

#define BB 8
#define CC 16
#define HH 512
#define WW 512
#define TIL 32
#define RAD 4
#define REG (TIL + 2*RAD)   // 40
#define NSRC (REG*REG)      // 1600
#define NTHR 256
#define ACCN (TIL*TIL*CC)   // 16384 floats = 64 KB

__global__ __launch_bounds__(NTHR, 2) void fwarp_tile(
    const float* __restrict__ im0,
    const float* __restrict__ flow,
    float* __restrict__ out)
{
    __shared__ float s_acc[ACCN];   // [c][32*32], plane-major

    const int tid  = threadIdx.x;
    const int tile = blockIdx.x;    // 8 * 16 * 16 = 2048
    const int tcx  = tile & 15;
    const int tcy  = (tile >> 4) & 15;
    const int b    = tile >> 8;
    const int w0   = tcx * TIL;
    const int h0   = tcy * TIL;

    // zero the accumulator (float4 stores)
    {
        float4 z; z.x = 0.f; z.y = 0.f; z.z = 0.f; z.w = 0.f;
        float4* av4 = (float4*)s_acc;
        #pragma unroll
        for (int j = 0; j < ACCN / 4 / NTHR; ++j)   // 16 per thread
            av4[tid + j * NTHR] = z;
    }
    __syncthreads();

    const float2* flow2 = (const float2*)flow + ((size_t)b << 18);
    const float*  imb   = im0 + ((size_t)(b * CC) << 18);

    for (int i = tid; i < NSRC; i += NTHR) {        // 7 iterations
        const int ry = i / REG;
        const int rx = i - ry * REG;
        const int sy = h0 - RAD + ry;
        const int sx = w0 - RAD + rx;
        if (sx < 0 || sx >= WW || sy < 0 || sy >= HH) continue;

        const int spatial = (sy << 9) + sx;
        const float2 f = flow2[spatial];
        // main path covers flow in [-RAD, RAD); rest -> fallback kernel
        if (!(f.x >= -(float)RAD && f.x < (float)RAD &&
              f.y >= -(float)RAD && f.y < (float)RAD)) continue;

        const float x = (float)sx + f.x;
        const float y = (float)sy + f.y;
        const float x0f = floorf(x);
        const float y0f = floorf(y);
        const int x0 = (int)x0f;
        const int y0 = (int)y0f;
        // reference scatters only if ALL four corners are in the image
        const bool valid = (x0 >= 0) & (x0 <= WW - 2) & (y0 >= 0) & (y0 <= HH - 2);

        const float fx = x - x0f;
        const float fy = y - y0f;
        const int lx = x0 - w0;     // NW corner, tile-local
        const int ly = y0 - h0;

        const bool okW = (lx >= 0) & (lx < TIL);
        const bool okE = (lx + 1 >= 0) & (lx + 1 < TIL);
        const bool okN = (ly >= 0) & (ly < TIL);
        const bool okS = (ly + 1 >= 0) & (ly + 1 < TIL);

        const float wnw = (valid && okN && okW) ? (1.0f - fx) * (1.0f - fy) : 0.0f;
        const float wne = (valid && okN && okE) ? fx * (1.0f - fy)          : 0.0f;
        const float wsw = (valid && okS && okW) ? (1.0f - fx) * fy          : 0.0f;
        const float wse = (valid && okS && okE) ? fx * fy                   : 0.0f;

        if (wnw == 0.0f && wne == 0.0f && wsw == 0.0f && wse == 0.0f) continue;

        // per-corner clamped addresses: a genuinely-used corner is already
        // in [0,TIL); clamping only relocates weight-0 adds to a safe slot.
        const int cx0 = min(max(lx,     0), TIL - 1);
        const int cx1 = min(max(lx + 1, 0), TIL - 1);
        const int cy0 = min(max(ly,     0), TIL - 1);
        const int cy1 = min(max(ly + 1, 0), TIL - 1);
        const int aNW = cy0 * TIL + cx0;
        const int aNE = cy0 * TIL + cx1;
        const int aSW = cy1 * TIL + cx0;
        const int aSE = cy1 * TIL + cx1;

        // 16 independent plane-strided loads -> one latency window
        const float* srcp = imb + spatial;
        float v[CC];
        #pragma unroll
        for (int c = 0; c < CC; ++c)
            v[c] = srcp[(size_t)c << 18];

        #pragma unroll
        for (int c = 0; c < CC; ++c) {
            float* a = s_acc + c * (TIL * TIL);
            atomicAdd(a + aNW, wnw * v[c]);
            atomicAdd(a + aNE, wne * v[c]);
            atomicAdd(a + aSW, wsw * v[c]);
            atomicAdd(a + aSE, wse * v[c]);
        }
    }
    __syncthreads();

    // writeout: one float4 per channel per thread, coalesced, exactly once
    const int dy  = tid >> 3;       // 0..31
    const int dx4 = tid & 7;        // 0..7  (8 float4 per 32-wide row)
    #pragma unroll
    for (int c = 0; c < CC; ++c) {
        const float4 vv = ((const float4*)s_acc)[c * 256 + tid];
        float* outc = out + (((size_t)(b * CC + c)) << 18);
        ((float4*)(outc + ((h0 + dy) << 9) + w0))[dx4] = vv;
    }
}

// Exact fallback for sources with flow outside [-RAD, RAD): global atomic scatter.
__global__ __launch_bounds__(256) void fwarp_fallback(
    const float* __restrict__ im0,
    const float* __restrict__ flow,
    float* __restrict__ out)
{
    const int idx = blockIdx.x * blockDim.x + threadIdx.x;  // b*H*W + h*W + w
    const int w = idx & (WW - 1);
    const int h = (idx >> 9) & (HH - 1);
    const int b = idx >> 18;

    const float2 f = ((const float2*)flow)[idx];
    const bool inrange = (f.x >= -(float)RAD) & (f.x < (float)RAD) &
                         (f.y >= -(float)RAD) & (f.y < (float)RAD);
    if (inrange) return;  // handled by fwarp_tile

    const float x = (float)w + f.x;
    const float y = (float)h + f.y;
    const float x0f = floorf(x);
    const float y0f = floorf(y);
    const int x0 = (int)x0f;
    const int y0 = (int)y0f;
    if (x0 < 0 || x0 > WW - 2 || y0 < 0 || y0 > HH - 2) return;

    const float fx = x - x0f;
    const float fy = y - y0f;
    const float wnw = (1.0f - fx) * (1.0f - fy);
    const float wne = fx * (1.0f - fy);
    const float wsw = (1.0f - fx) * fy;
    const float wse = fx * fy;

    const size_t plane = (size_t)HH * WW;
    const float* srcb = im0 + (size_t)b * CC * plane + (size_t)h * WW + w;
    float* dstb       = out + (size_t)b * CC * plane;
    const int o = y0 * WW + x0;

#pragma unroll
    for (int c = 0; c < CC; ++c) {
        const float v = srcb[c * plane];
        float* dc = dstb + c * plane;
        atomicAdd(dc + o,          v * wnw);
        atomicAdd(dc + o + 1,      v * wne);
        atomicAdd(dc + o + WW,     v * wsw);
        atomicAdd(dc + o + WW + 1, v * wse);
    }
}

extern "C" void kernel_launch(void* const* d_in, const int* in_sizes, int n_in,
                              void* d_out, int out_size, void* d_ws, size_t ws_size,
                              hipStream_t stream) {
    const float* im0  = (const float*)d_in[0];
    const float* flow = (const float*)d_in[1];
    float* out = (float*)d_out;

    // Main kernel writes every output element exactly once -> no memset needed.
    const int n_tiles = BB * (HH / TIL) * (WW / TIL);  // 2048
    fwarp_tile<<<n_tiles, NTHR, 0, stream>>>(im0, flow, out);

    // Rare long-range sources: exact global-atomic scatter, ordered after.
    const int n_pix = BB * HH * WW;
    fwarp_fallback<<<n_pix / 256, 256, 0, stream>>>(im0, flow, out);
}